// Round 1
// baseline (87.026 us; speedup 1.0000x reference)
//
#include <hip/hip_runtime.h>
#include <math.h>

#define DD 2048
#define DTC 0.01f
#define NSTEPS 30

__device__ __forceinline__ void lorenz_deriv(float x, float y, float z,
                                             float sigma, float rho, float beta,
                                             float& dx, float& dy, float& dz) {
    dx = sigma * (y - x);
    dy = x * (rho - z) - y;
    dz = x * y - beta * z;
}

__device__ __forceinline__ float fast_tanh(float p) {
    // tanh(p) = 1 - 2/(exp(2p)+1); saturates correctly for |p| large.
    float e = __expf(2.0f * p);
    return 1.0f - __fdividef(2.0f, e + 1.0f);
}

// K1: 8 rows per block. Compute state0 = x_row . W_in^T + b_in via block-wide
// reduction, then lanes 0..7 of wave 0 each integrate one row's Lorenz RK4
// (30 steps) with streaming stats, writing 18 features per row to ws.
__global__ __launch_bounds__(256) void k1_feats(
    const float* __restrict__ x, const float* __restrict__ lorenz,
    const float* __restrict__ W_in, const float* __restrict__ b_in,
    float* __restrict__ feats) {
    const int tid = threadIdx.x;
    const int row0 = blockIdx.x * 8;
    const int d0 = tid * 8;

    // W_in slice for this thread's 8 columns (reused across 8 rows)
    float w0[8], w1[8], w2[8];
    {
        const float4* p0 = reinterpret_cast<const float4*>(W_in + 0 * DD + d0);
        const float4* p1 = reinterpret_cast<const float4*>(W_in + 1 * DD + d0);
        const float4* p2 = reinterpret_cast<const float4*>(W_in + 2 * DD + d0);
        float4 a, b;
        a = p0[0]; b = p0[1];
        w0[0]=a.x; w0[1]=a.y; w0[2]=a.z; w0[3]=a.w; w0[4]=b.x; w0[5]=b.y; w0[6]=b.z; w0[7]=b.w;
        a = p1[0]; b = p1[1];
        w1[0]=a.x; w1[1]=a.y; w1[2]=a.z; w1[3]=a.w; w1[4]=b.x; w1[5]=b.y; w1[6]=b.z; w1[7]=b.w;
        a = p2[0]; b = p2[1];
        w2[0]=a.x; w2[1]=a.y; w2[2]=a.z; w2[3]=a.w; w2[4]=b.x; w2[5]=b.y; w2[6]=b.z; w2[7]=b.w;
    }

    float part[8][3];
#pragma unroll
    for (int r = 0; r < 8; ++r) {
        const float4* p = reinterpret_cast<const float4*>(x + (size_t)(row0 + r) * DD + d0);
        float4 a = p[0], b = p[1];
        float xv[8] = {a.x, a.y, a.z, a.w, b.x, b.y, b.z, b.w};
        float s0 = 0.f, s1 = 0.f, s2 = 0.f;
#pragma unroll
        for (int j = 0; j < 8; ++j) {
            s0 += xv[j] * w0[j];
            s1 += xv[j] * w1[j];
            s2 += xv[j] * w2[j];
        }
        part[r][0] = s0; part[r][1] = s1; part[r][2] = s2;
    }

    __shared__ float red[4][24];
    __shared__ float st0[8][3];
    const int lane = tid & 63;
    const int wv = tid >> 6;
#pragma unroll
    for (int r = 0; r < 8; ++r) {
#pragma unroll
        for (int k = 0; k < 3; ++k) {
            float v = part[r][k];
#pragma unroll
            for (int off = 32; off > 0; off >>= 1) v += __shfl_xor(v, off, 64);
            if (lane == 0) red[wv][r * 3 + k] = v;
        }
    }
    __syncthreads();
    if (tid < 24) {
        float v = red[0][tid] + red[1][tid] + red[2][tid] + red[3][tid] + b_in[tid % 3];
        st0[tid / 3][tid % 3] = v;
    }
    __syncthreads();

    if (tid < 8) {
        const float sigma = fmaxf(fabsf(lorenz[0]), 0.1f);
        const float rho   = fmaxf(fabsf(lorenz[1]), 0.1f);
        const float beta  = fmaxf(fabsf(lorenz[2]), 0.1f);
        float sx = st0[tid][0], sy = st0[tid][1], sz = st0[tid][2];
        const float ix = sx, iy = sy, iz = sz;
        float sux = sx, suy = sy, suz = sz;
        float sqx = sx * sx, sqy = sy * sy, sqz = sz * sz;
        float mnx = sx, mny = sy, mnz = sz;
        float mxx = sx, mxy = sy, mxz = sz;
#pragma unroll 1
        for (int t = 0; t < NSTEPS; ++t) {
            float k1x, k1y, k1z, k2x, k2y, k2z, k3x, k3y, k3z, k4x, k4y, k4z;
            float ax, ay, az;
            lorenz_deriv(sx, sy, sz, sigma, rho, beta, k1x, k1y, k1z);
            ax = sx + 0.5f * DTC * k1x; ay = sy + 0.5f * DTC * k1y; az = sz + 0.5f * DTC * k1z;
            lorenz_deriv(ax, ay, az, sigma, rho, beta, k2x, k2y, k2z);
            ax = sx + 0.5f * DTC * k2x; ay = sy + 0.5f * DTC * k2y; az = sz + 0.5f * DTC * k2z;
            lorenz_deriv(ax, ay, az, sigma, rho, beta, k3x, k3y, k3z);
            ax = sx + DTC * k3x; ay = sy + DTC * k3y; az = sz + DTC * k3z;
            lorenz_deriv(ax, ay, az, sigma, rho, beta, k4x, k4y, k4z);
            sx += (DTC / 6.0f) * (k1x + 2.0f * k2x + 2.0f * k3x + k4x);
            sy += (DTC / 6.0f) * (k1y + 2.0f * k2y + 2.0f * k3y + k4y);
            sz += (DTC / 6.0f) * (k1z + 2.0f * k2z + 2.0f * k3z + k4z);
            sux += sx; suy += sy; suz += sz;
            sqx += sx * sx; sqy += sy * sy; sqz += sz * sz;
            mnx = fminf(mnx, sx); mny = fminf(mny, sy); mnz = fminf(mnz, sz);
            mxx = fmaxf(mxx, sx); mxy = fmaxf(mxy, sy); mxz = fmaxf(mxz, sz);
        }
        const float inv31 = 1.0f / 31.0f;
        const float inv30 = 1.0f / 30.0f;
        const float mex = sux * inv31, mey = suy * inv31, mez = suz * inv31;
        const float vax = fmaxf((sqx - sux * mex) * inv30, 0.0f);
        const float vay = fmaxf((sqy - suy * mey) * inv30, 0.0f);
        const float vaz = fmaxf((sqz - suz * mez) * inv30, 0.0f);
        float* f = feats + (size_t)(row0 + tid) * 18;
        f[0]  = ix;  f[1]  = iy;  f[2]  = iz;
        f[3]  = sx;  f[4]  = sy;  f[5]  = sz;
        f[6]  = mex; f[7]  = mey; f[8]  = mez;
        f[9]  = sqrtf(vax); f[10] = sqrtf(vay); f[11] = sqrtf(vaz);
        f[12] = mnx; f[13] = mny; f[14] = mnz;
        f[15] = mxx; f[16] = mxy; f[17] = mxz;
    }
}

// K2: tile 32 rows x 512 cols per block (256 threads, 2 cols/thread).
// W_out rows held in registers; feats loads are wave-uniform (scalarizable).
__global__ __launch_bounds__(256) void k2_out(
    const float* __restrict__ x, const float* __restrict__ feats,
    const float* __restrict__ W_out, const float* __restrict__ b_out,
    const float* __restrict__ strength, float* __restrict__ out) {
    const int tid = threadIdx.x;
    const int row0 = blockIdx.x * 32;
    const int j0 = blockIdx.y * 512 + tid * 2;

    float w0[18], w1[18];
    {
        const float* wp = W_out + (size_t)j0 * 18;
#pragma unroll
        for (int k = 0; k < 18; ++k) { w0[k] = wp[k]; w1[k] = wp[18 + k]; }
    }
    const float2 bo = *reinterpret_cast<const float2*>(b_out + j0);
    const float sabs = fabsf(strength[0]);

#pragma unroll 1
    for (int r = 0; r < 32; ++r) {
        const int row = row0 + r;
        const float* f = feats + (size_t)row * 18;
        float p0 = bo.x, p1 = bo.y;
#pragma unroll
        for (int k = 0; k < 18; ++k) {
            const float fk = f[k];
            p0 += fk * w0[k];
            p1 += fk * w1[k];
        }
        const float2 xv = *reinterpret_cast<const float2*>(x + (size_t)row * DD + j0);
        float2 o;
        o.x = xv.x + fast_tanh(p0) * sabs;
        o.y = xv.y + fast_tanh(p1) * sabs;
        *reinterpret_cast<float2*>(out + (size_t)row * DD + j0) = o;
    }
}

extern "C" void kernel_launch(void* const* d_in, const int* in_sizes, int n_in,
                              void* d_out, int out_size, void* d_ws, size_t ws_size,
                              hipStream_t stream) {
    const float* x        = (const float*)d_in[0];
    const float* lorenz   = (const float*)d_in[1];
    const float* strength = (const float*)d_in[2];
    const float* W_in     = (const float*)d_in[3];
    const float* b_in     = (const float*)d_in[4];
    const float* W_out    = (const float*)d_in[5];
    const float* b_out    = (const float*)d_in[6];
    float* out   = (float*)d_out;
    float* feats = (float*)d_ws;   // N*18 floats = 1.18 MB

    const int N = in_sizes[0] / DD;  // 16384

    k1_feats<<<N / 8, 256, 0, stream>>>(x, lorenz, W_in, b_in, feats);

    dim3 g2(N / 32, DD / 512);
    k2_out<<<g2, 256, 0, stream>>>(x, feats, W_out, b_out, strength, out);
}